// Round 1
// baseline (539.234 us; speedup 1.0000x reference)
//
#include <hip/hip_runtime.h>

#define CH 16
#define NB 8
#define G0 64

// ---------------- Stem: 5x5x5 conv, 1->16 ch, SAME, + mask + ReLU ----------
__global__ __launch_bounds__(512) void stem_kernel(
    const float* __restrict__ x, const int* __restrict__ mask,
    const float* __restrict__ wst, float* __restrict__ yout)
{
  __shared__ float tile[12 * 12 * 12];
  const int b = blockIdx.y;
  const int tb = blockIdx.x;               // 512 tiles of 8x8x8
  const int z0 = ((tb >> 6) & 7) * 8;
  const int y0 = ((tb >> 3) & 7) * 8;
  const int x0 = (tb & 7) * 8;
  const int tid = threadIdx.x;

  for (int i = tid; i < 1728; i += 512) {
    const int lz = i / 144;
    const int ly = (i / 12) % 12;
    const int lx = i % 12;
    const int gz = z0 + lz - 2, gy = y0 + ly - 2, gx = x0 + lx - 2;
    float v = 0.f;
    if ((unsigned)gz < G0 && (unsigned)gy < G0 && (unsigned)gx < G0) {
      const int gi = ((b * G0 + gz) * G0 + gy) * G0 + gx;
      v = x[gi] * (float)mask[gi];
    }
    tile[i] = v;
  }
  __syncthreads();

  const int lz = tid >> 6, ly = (tid >> 3) & 7, lx = tid & 7;
  float acc[CH];
#pragma unroll
  for (int c = 0; c < CH; ++c) acc[c] = 0.f;

  for (int dz = 0; dz < 5; ++dz)
    for (int dy = 0; dy < 5; ++dy)
#pragma unroll
      for (int dx = 0; dx < 5; ++dx) {
        const float v = tile[(lz + dz) * 144 + (ly + dy) * 12 + (lx + dx)];
        const float* wp = wst + ((dz * 5 + dy) * 5 + dx) * CH;
#pragma unroll
        for (int c = 0; c < CH; ++c) acc[c] = fmaf(v, wp[c], acc[c]);
      }

  const int gz = z0 + lz, gy = y0 + ly, gx = x0 + lx;
  const int gi = ((b * G0 + gz) * G0 + gy) * G0 + gx;
  const float mv = (float)mask[gi];
#pragma unroll
  for (int c = 0; c < CH; ++c) acc[c] = fmaxf(acc[c], 0.f) * mv;

  float* op = yout + (size_t)gi * CH;
  ((float4*)op)[0] = make_float4(acc[0], acc[1], acc[2], acc[3]);
  ((float4*)op)[1] = make_float4(acc[4], acc[5], acc[6], acc[7]);
  ((float4*)op)[2] = make_float4(acc[8], acc[9], acc[10], acc[11]);
  ((float4*)op)[3] = make_float4(acc[12], acc[13], acc[14], acc[15]);
}

// ------------- Stage: 3x3x3 stride-2 conv 16->16 + mask pool + ReLU + pool sums
__global__ __launch_bounds__(256) void stage_kernel(
    const float* __restrict__ yin, const float* __restrict__ w,
    const int* __restrict__ m_in_i, const float* __restrict__ m_in_f,
    float* __restrict__ yout, float* __restrict__ m_out,
    float* __restrict__ pool_sum, float* __restrict__ cnt,
    const int S, const int stage)
{
  const int So = S >> 1;
  const int nvox = So * So * So;
  const int b = blockIdx.y;
  const int vid = blockIdx.x * 256 + (int)threadIdx.x;
  const bool active = vid < nvox;
  const int cv = active ? vid : 0;
  const int oz = cv / (So * So);
  const int oy = (cv / So) % So;
  const int ox = cv % So;

  float acc[CH];
#pragma unroll
  for (int c = 0; c < CH; ++c) acc[c] = 0.f;

  for (int dz = 0; dz < 3; ++dz)
    for (int dy = 0; dy < 3; ++dy)
      for (int dx = 0; dx < 3; ++dx) {
        const int iz = 2 * oz + dz - 1;
        const int iy = 2 * oy + dy - 1;
        const int ix = 2 * ox + dx - 1;
        const bool inb = active && (unsigned)iz < (unsigned)S &&
                         (unsigned)iy < (unsigned)S && (unsigned)ix < (unsigned)S;
        float4 v0, v1, v2, v3;
        if (inb) {
          const float* ip =
              yin + (size_t)(((b * S + iz) * S + iy) * S + ix) * CH;
          v0 = ((const float4*)ip)[0];
          v1 = ((const float4*)ip)[1];
          v2 = ((const float4*)ip)[2];
          v3 = ((const float4*)ip)[3];
        } else {
          v0 = v1 = v2 = v3 = make_float4(0.f, 0.f, 0.f, 0.f);
        }
        const float iv[CH] = {v0.x, v0.y, v0.z, v0.w, v1.x, v1.y, v1.z, v1.w,
                              v2.x, v2.y, v2.z, v2.w, v3.x, v3.y, v3.z, v3.w};
        const float* wp = w + ((dz * 3 + dy) * 3 + dx) * 256;
#pragma unroll
        for (int ci = 0; ci < CH; ++ci) {
          const float v = iv[ci];
#pragma unroll
          for (int co = 0; co < CH; ++co)
            acc[co] = fmaf(v, wp[ci * 16 + co], acc[co]);
        }
      }

  // 2x2x2 max-pool of the mask (window [2o, 2o+1], S even -> no clipping)
  float mp = 0.f;
  if (active) {
#pragma unroll
    for (int dz = 0; dz < 2; ++dz)
#pragma unroll
      for (int dy = 0; dy < 2; ++dy)
#pragma unroll
        for (int dx = 0; dx < 2; ++dx) {
          const int mi =
              ((b * S + 2 * oz + dz) * S + 2 * oy + dy) * S + 2 * ox + dx;
          const float mvv = m_in_i ? (float)m_in_i[mi] : m_in_f[mi];
          mp = fmaxf(mp, mvv);
        }
  }

#pragma unroll
  for (int c = 0; c < CH; ++c) acc[c] = fmaxf(acc[c], 0.f) * mp;

  if (active) {
    float* op = yout + (size_t)(b * nvox + vid) * CH;
    ((float4*)op)[0] = make_float4(acc[0], acc[1], acc[2], acc[3]);
    ((float4*)op)[1] = make_float4(acc[4], acc[5], acc[6], acc[7]);
    ((float4*)op)[2] = make_float4(acc[8], acc[9], acc[10], acc[11]);
    ((float4*)op)[3] = make_float4(acc[12], acc[13], acc[14], acc[15]);
    m_out[b * nvox + vid] = mp;
  }

  // block-level reduction of channel sums + occupancy count -> atomics
  const int lane = threadIdx.x & 63;
  const int wv = threadIdx.x >> 6;
  __shared__ float rsum[4][CH];
  __shared__ float rcnt[4];

  float csum[CH];
#pragma unroll
  for (int c = 0; c < CH; ++c) {
    float v = acc[c];
#pragma unroll
    for (int off = 32; off > 0; off >>= 1) v += __shfl_xor(v, off, 64);
    csum[c] = v;
  }
  float cc = active ? mp : 0.f;
#pragma unroll
  for (int off = 32; off > 0; off >>= 1) cc += __shfl_xor(cc, off, 64);

  if (lane == 0) {
#pragma unroll
    for (int c = 0; c < CH; ++c) rsum[wv][c] = csum[c];
    rcnt[wv] = cc;
  }
  __syncthreads();
  if (threadIdx.x < CH) {
    const float t = rsum[0][threadIdx.x] + rsum[1][threadIdx.x] +
                    rsum[2][threadIdx.x] + rsum[3][threadIdx.x];
    atomicAdd(&pool_sum[(b * 6 + stage) * CH + (int)threadIdx.x], t);
  } else if (threadIdx.x == CH) {
    atomicAdd(&cnt[b * 6 + stage], rcnt[0] + rcnt[1] + rcnt[2] + rcnt[3]);
  }
}

// ---------------- Head: meta MLP + mat/sched/fuse MLPs ---------------------
__global__ __launch_bounds__(128) void head_kernel(
    const float* __restrict__ meta, const float* __restrict__ sched,
    const float* __restrict__ mw1, const float* __restrict__ mb1,
    const float* __restrict__ mw2, const float* __restrict__ mb2,
    const float* __restrict__ matw, const float* __restrict__ matb,
    const float* __restrict__ schw, const float* __restrict__ schb,
    const float* __restrict__ f1w, const float* __restrict__ f1b,
    const float* __restrict__ f2w, const float* __restrict__ f2b,
    const float* __restrict__ pool_sum, const float* __restrict__ cnt,
    float* __restrict__ out)
{
  const int b = blockIdx.x;
  const int t = threadIdx.x;
  __shared__ float invec[112];
  __shared__ float hbuf[32];
  __shared__ float zbuf[256];
  __shared__ float part[2];

  if (t < 96) {
    const int s = t >> 4;
    const float d = fmaxf(cnt[b * 6 + s], 1.f);
    invec[t] = pool_sum[b * 96 + t] / d;
  }
  if (t < 32) {
    float h = mb1[t];
#pragma unroll
    for (int j = 0; j < 3; ++j) h = fmaf(meta[b * 3 + j], mw1[j * 32 + t], h);
    hbuf[t] = fmaxf(h, 0.f);
  }
  __syncthreads();
  if (t < 16) {
    float e = mb2[t];
#pragma unroll
    for (int j = 0; j < 32; ++j) e = fmaf(hbuf[j], mw2[j * 16 + t], e);
    invec[96 + t] = e;  // no ReLU on meta_emb
  }
  __syncthreads();
  {
    float a = matb[t];
    for (int k = 0; k < 112; ++k) a = fmaf(invec[k], matw[k * 128 + t], a);
    zbuf[t] = fmaxf(a, 0.f);
    float s = schb[t];
    for (int k = 0; k < 128; ++k)
      s = fmaf(sched[b * 128 + k], schw[k * 128 + t], s);
    zbuf[128 + t] = fmaxf(s, 0.f);
  }
  __syncthreads();
  float a = f1b[t];
  for (int k = 0; k < 256; ++k) a = fmaf(zbuf[k], f1w[k * 128 + t], a);
  float v = fmaxf(a, 0.f) * f2w[t];
#pragma unroll
  for (int off = 32; off > 0; off >>= 1) v += __shfl_xor(v, off, 64);
  if ((t & 63) == 0) part[t >> 6] = v;
  __syncthreads();
  if (t == 0) out[b] = part[0] + part[1] + f2b[0];
}

extern "C" void kernel_launch(void* const* d_in, const int* in_sizes, int n_in,
                              void* d_out, int out_size, void* d_ws,
                              size_t ws_size, hipStream_t stream)
{
  (void)in_sizes; (void)n_in; (void)out_size; (void)ws_size;
  const float* x      = (const float*)d_in[0];
  const int*   mask   = (const int*)  d_in[1];
  const float* meta   = (const float*)d_in[2];
  const float* sched  = (const float*)d_in[3];
  const float* w_stem = (const float*)d_in[4];
  const float* w_stg  = (const float*)d_in[5];
  const float* mw1    = (const float*)d_in[6];
  const float* mb1    = (const float*)d_in[7];
  const float* mw2    = (const float*)d_in[8];
  const float* mb2    = (const float*)d_in[9];
  const float* matw   = (const float*)d_in[10];
  const float* matb   = (const float*)d_in[11];
  const float* schw   = (const float*)d_in[12];
  const float* schb   = (const float*)d_in[13];
  const float* f1w    = (const float*)d_in[14];
  const float* f1b    = (const float*)d_in[15];
  const float* f2w    = (const float*)d_in[16];
  const float* f2b    = (const float*)d_in[17];
  float* out = (float*)d_out;

  char* ws = (char*)d_ws;
  size_t off = 0;
  auto alloc = [&](size_t nbytes) -> void* {
    void* p = ws + off;
    off += (nbytes + 255) & ~(size_t)255;
    return p;
  };

  float* y[7];
  y[0] = (float*)alloc((size_t)NB * 64 * 64 * 64 * CH * 4);
  float* mout[7] = {nullptr, nullptr, nullptr, nullptr, nullptr, nullptr, nullptr};
  for (int s = 1; s <= 6; ++s) {
    const int So = 64 >> s;
    y[s] = (float*)alloc((size_t)NB * So * So * So * CH * 4);
    mout[s] = (float*)alloc((size_t)NB * So * So * So * 4);
  }
  float* pool_sum = (float*)alloc((NB * 96 + NB * 6) * 4);
  float* cnt = pool_sum + NB * 96;

  hipMemsetAsync(pool_sum, 0, (NB * 96 + NB * 6) * 4, stream);

  stem_kernel<<<dim3(512, NB), 512, 0, stream>>>(x, mask, w_stem, y[0]);

  for (int s = 0; s < 6; ++s) {
    const int Si = 64 >> s;
    const int So = Si >> 1;
    const int nvox = So * So * So;
    dim3 grid((nvox + 255) / 256, NB);
    stage_kernel<<<grid, 256, 0, stream>>>(
        y[s], w_stg + (size_t)s * 27 * 256,
        s == 0 ? mask : (const int*)nullptr,
        s == 0 ? (const float*)nullptr : mout[s],
        y[s + 1], mout[s + 1], pool_sum, cnt, Si, s);
  }

  head_kernel<<<NB, 128, 0, stream>>>(meta, sched, mw1, mb1, mw2, mb2,
                                      matw, matb, schw, schb,
                                      f1w, f1b, f2w, f2b, pool_sum, cnt, out);
}